// Round 13
// baseline (373.206 us; speedup 1.0000x reference)
//
#include <hip/hip_runtime.h>

// GCN-VAE encoder forward on MI355X — R16: gemm_bfin back to BM=64.
//
// agg[d] = dinv[d] * ( dinv[d]*h[d] + sum_s dinv[s]*h[s] )
//
// R16: gemm_mfma_bfin still carried R12's BM=128/64KB geometry that R15
//   proved latency-bound (2 blocks/CU can't hide the per-k-step vmcnt(0)
//   drain; K=128 -> only 4 k-steps). Revert to R6's BM=64/48KB geometry ->
//   3 blocks/CU = 12 waves/CU, finer tail. Single-variable experiment.
//
// R15: csr_gemm1 gemm path BM=64 + 48KB LDS union with csr path.
// R14: prep||partition fused; build_csr||gemm1 fused (dinv folded into
//   gather_hidden's fma-gather). R13: fixed-capacity staged spans.
// R11: shfl-shared gather indices. R9: NO gather/GEMM occupancy fusion.
// R8: gathers at random-256B wall (~66-68us each; 4 null experiments).
//
// ws: hs1[N*128]bf | hidH | hidL | hs2 (aliased staged during CSR build) |
//     cnt[N] | dinv[N] | rowptr[N] | cursor (gcur[256]) | bsum[512] |
//     bcat[128] | w1t_h/l | wct_h/l | csr[E]

#define TPB 256
#define GSHIFT 9
#define GSIZE 512
#define PART_M 4096   // edges per partition WG
#define GCAP 12288    // fixed staged span per group
#define NPREP 192     // prep blocks in kernel A

typedef __attribute__((ext_vector_type(8))) short short8;
typedef __attribute__((ext_vector_type(4))) short short4v;
typedef __attribute__((ext_vector_type(4))) float floatx4;
typedef __attribute__((ext_vector_type(4))) unsigned int uint4v;

__device__ __forceinline__ void split2(float v, short& hi, short& lo) {
    unsigned u = __float_as_uint(v);
    float hf = __uint_as_float(u & 0xFFFF0000u);
    float lf = v - hf;                       // exact
    hi = (short)(u >> 16);
    lo = (short)(__float_as_uint(lf) >> 16);
}

__device__ __forceinline__ short bf16_rtn(float v) {
    unsigned u = __float_as_uint(v);
    u += 0x7FFF + ((u >> 16) & 1);           // round to nearest even
    return (short)(u >> 16);
}

__device__ __forceinline__ void addrow(float* a, uint4v v) {
    a[0] += __uint_as_float(v[0] << 16); a[1] += __uint_as_float(v[0] & 0xFFFF0000u);
    a[2] += __uint_as_float(v[1] << 16); a[3] += __uint_as_float(v[1] & 0xFFFF0000u);
    a[4] += __uint_as_float(v[2] << 16); a[5] += __uint_as_float(v[2] & 0xFFFF0000u);
    a[6] += __uint_as_float(v[3] << 16); a[7] += __uint_as_float(v[3] & 0xFFFF0000u);
}

// scaled accumulate: a += s * row
__device__ __forceinline__ void addrow_s(float* a, uint4v v, float s) {
    a[0] = fmaf(s, __uint_as_float(v[0] << 16), a[0]);
    a[1] = fmaf(s, __uint_as_float(v[0] & 0xFFFF0000u), a[1]);
    a[2] = fmaf(s, __uint_as_float(v[1] << 16), a[2]);
    a[3] = fmaf(s, __uint_as_float(v[1] & 0xFFFF0000u), a[3]);
    a[4] = fmaf(s, __uint_as_float(v[2] << 16), a[4]);
    a[5] = fmaf(s, __uint_as_float(v[2] & 0xFFFF0000u), a[5]);
    a[6] = fmaf(s, __uint_as_float(v[3] << 16), a[6]);
    a[7] = fmaf(s, __uint_as_float(v[3] & 0xFFFF0000u), a[7]);
}

// unscaled gather (gather_out: hs2 already carries dinv)
__device__ __forceinline__ void gather_accum(float* acc, const int* __restrict__ csr,
                                             int start, int deg, const uint4v* hp,
                                             int l16) {
    for (int jj = 0; jj < deg; jj += 16) {
        int rem = deg - jj;
        if (rem > 16) rem = 16;
        int il = (l16 < rem) ? l16 : rem - 1;
        int myIdx = csr[start + jj + il];
        int r = 0;
        for (; r + 3 < rem; r += 4) {
            int i0 = __shfl(myIdx, r + 0, 16);
            int i1 = __shfl(myIdx, r + 1, 16);
            int i2 = __shfl(myIdx, r + 2, 16);
            int i3 = __shfl(myIdx, r + 3, 16);
            uint4v v0 = hp[(size_t)i0 * 16 + l16];
            uint4v v1 = hp[(size_t)i1 * 16 + l16];
            uint4v v2 = hp[(size_t)i2 * 16 + l16];
            uint4v v3 = hp[(size_t)i3 * 16 + l16];
            addrow(acc, v0);
            addrow(acc, v1);
            addrow(acc, v2);
            addrow(acc, v3);
        }
        for (; r < rem; ++r) {
            int i = __shfl(myIdx, r, 16);
            addrow(acc, hp[(size_t)i * 16 + l16]);
        }
    }
}

// dinv-scaled gather (gather_hidden: rows are raw h, scale by dinv[s])
__device__ __forceinline__ void gather_accum_s(float* acc, const int* __restrict__ csr,
                                               const float* __restrict__ dinv,
                                               int start, int deg, const uint4v* hp,
                                               int l16) {
    for (int jj = 0; jj < deg; jj += 16) {
        int rem = deg - jj;
        if (rem > 16) rem = 16;
        int il = (l16 < rem) ? l16 : rem - 1;
        int myIdx = csr[start + jj + il];
        float myD = dinv[myIdx];
        int r = 0;
        for (; r + 3 < rem; r += 4) {
            int i0 = __shfl(myIdx, r + 0, 16);
            int i1 = __shfl(myIdx, r + 1, 16);
            int i2 = __shfl(myIdx, r + 2, 16);
            int i3 = __shfl(myIdx, r + 3, 16);
            float d0 = __shfl(myD, r + 0, 16);
            float d1 = __shfl(myD, r + 1, 16);
            float d2 = __shfl(myD, r + 2, 16);
            float d3 = __shfl(myD, r + 3, 16);
            uint4v v0 = hp[(size_t)i0 * 16 + l16];
            uint4v v1 = hp[(size_t)i1 * 16 + l16];
            uint4v v2 = hp[(size_t)i2 * 16 + l16];
            uint4v v3 = hp[(size_t)i3 * 16 + l16];
            addrow_s(acc, v0, d0);
            addrow_s(acc, v1, d1);
            addrow_s(acc, v2, d2);
            addrow_s(acc, v3, d3);
        }
        for (; r < rem; ++r) {
            int i = __shfl(myIdx, r, 16);
            float d = __shfl(myD, r, 16);
            addrow_s(acc, hp[(size_t)i * 16 + l16], d);
        }
    }
}

// async 16B global -> LDS (linear dest: wave-uniform base + lane*16)
__device__ __forceinline__ void gload_lds16(const void* g, void* l) {
    __builtin_amdgcn_global_load_lds(
        (const __attribute__((address_space(1))) unsigned int*)g,
        (__attribute__((address_space(3))) unsigned int*)l, 16, 0, 0);
}

// ---------------- kernel A: prep (blocks 0..191) || partition (rest) ----------------
__global__ __launch_bounds__(TPB) void prep_part(const float* __restrict__ w1,
                                                 const float* __restrict__ w2,
                                                 const float* __restrict__ b2,
                                                 const float* __restrict__ w3,
                                                 const float* __restrict__ b3,
                                                 short* __restrict__ w1t_h,
                                                 short* __restrict__ w1t_l,
                                                 short* __restrict__ wct_h,
                                                 short* __restrict__ wct_l,
                                                 float* __restrict__ bcat,
                                                 const int* __restrict__ src,
                                                 const int* __restrict__ dst,
                                                 int* __restrict__ gcur,
                                                 int* __restrict__ staged, int E) {
    __shared__ int sc[256];
    __shared__ int cur[256];
    __shared__ int gb[256];
    int b = blockIdx.x, t = threadIdx.x;
    if (b < 128) {
        int i = b * TPB + t;                 // < 128*256
        int k = i & 255, n = i >> 8;
        float v = w1[(size_t)k * 128 + n];
        short h, l;
        split2(v, h, l);
        w1t_h[i] = h;
        w1t_l[i] = l;
        return;
    } else if (b < NPREP) {
        int i = (b - 128) * TPB + t;         // < 128*128
        int k = i & 127, n = i >> 7;
        float v = (n < 64) ? w2[(size_t)k * 64 + n] : w3[(size_t)k * 64 + (n - 64)];
        short h, l;
        split2(v, h, l);
        wct_h[i] = h;
        wct_l[i] = l;
        if (i < 64) { bcat[i] = b2[i]; bcat[64 + i] = b3[i]; }
        return;
    }
    // ---- partition path ----
    int base = (b - NPREP) * PART_M;
    int mloc = min(PART_M, E - base);
    int m4 = mloc >> 2;
    sc[t] = 0;
    cur[t] = 0;
    __syncthreads();
    const int4* d4 = (const int4*)(dst + base);
    const int4* s4 = (const int4*)(src + base);
    for (int k = t; k < m4; k += 256) {
        int4 v = d4[k];
        atomicAdd(&sc[v.x >> GSHIFT], 1);
        atomicAdd(&sc[v.y >> GSHIFT], 1);
        atomicAdd(&sc[v.z >> GSHIFT], 1);
        atomicAdd(&sc[v.w >> GSHIFT], 1);
    }
    for (int k = (m4 << 2) + t; k < mloc; k += 256)
        atomicAdd(&sc[dst[base + k] >> GSHIFT], 1);
    __syncthreads();
    int v = sc[t];
    gb[t] = v ? t * GCAP + atomicAdd(&gcur[t], v) : 0;   // exclusive span slice
    __syncthreads();
    for (int k = t; k < m4; k += 256) {
        int4 dv = d4[k];
        int4 sv = s4[k];
        int b0 = dv.x >> GSHIFT;
        staged[gb[b0] + atomicAdd(&cur[b0], 1)] = (sv.x << GSHIFT) | (dv.x & (GSIZE - 1));
        int b1 = dv.y >> GSHIFT;
        staged[gb[b1] + atomicAdd(&cur[b1], 1)] = (sv.y << GSHIFT) | (dv.y & (GSIZE - 1));
        int b2_ = dv.z >> GSHIFT;
        staged[gb[b2_] + atomicAdd(&cur[b2_], 1)] = (sv.z << GSHIFT) | (dv.z & (GSIZE - 1));
        int b3_ = dv.w >> GSHIFT;
        staged[gb[b3_] + atomicAdd(&cur[b3_], 1)] = (sv.w << GSHIFT) | (dv.w & (GSIZE - 1));
    }
    for (int k = (m4 << 2) + t; k < mloc; k += 256) {
        int d = dst[base + k];
        int s = src[base + k];
        int bb = d >> GSHIFT;
        staged[gb[bb] + atomicAdd(&cur[bb], 1)] = (s << GSHIFT) | (d & (GSIZE - 1));
    }
}

// ---------------- kernel B: build_csr256 (blocks 0..ngrp) || gemm1 BM=64 (rest) ----------------
__global__ __launch_bounds__(TPB) void csr_gemm1(const int* __restrict__ staged,
                                                 const int* __restrict__ gcur,
                                                 int* __restrict__ cnt,
                                                 float* __restrict__ dinv,
                                                 int* __restrict__ rowptr,
                                                 int* __restrict__ csr,
                                                 const float* __restrict__ A,
                                                 const short* __restrict__ Bth,
                                                 const short* __restrict__ Btl,
                                                 short* __restrict__ Cb,
                                                 int N, int K, int ngrp) {
    __shared__ __align__(16) char smem[49152];   // 48KB union
    int t = threadIdx.x;

    if ((int)blockIdx.x < ngrp) {
        // ---- build_csr path (256 threads, one 512-node group; 8KB of smem) ----
        int* pre  = (int*)smem;        // [256]
        int* hist = pre + 256;         // [512]
        int* psum = hist + 512;        // [256]
        int* lrow = psum + 256;        // [512]
        int* curq = lrow + 512;        // [512]
        int g = blockIdx.x;
        pre[t] = (t < ngrp) ? gcur[t] : 0;
        hist[t] = 0;
        hist[t + 256] = 0;
        curq[t] = 0;
        curq[t + 256] = 0;
        __syncthreads();
#pragma unroll
        for (int off = 1; off < 256; off <<= 1) {
            int x = (t >= off) ? pre[t - off] : 0;
            __syncthreads();
            pre[t] += x;
            __syncthreads();
        }
        int count = gcur[g];
        int s0_out = pre[g] - count;     // exact exclusive offset into csr
        int s0_in = g * GCAP;
        for (int k = t; k < count; k += 256)
            atomicAdd(&hist[staged[s0_in + k] & (GSIZE - 1)], 1);
        __syncthreads();
        int h0 = hist[2 * t], h1 = hist[2 * t + 1];
        int ps = h0 + h1;
        psum[t] = ps;
        __syncthreads();
#pragma unroll
        for (int off = 1; off < 256; off <<= 1) {
            int x = (t >= off) ? psum[t - off] : 0;
            __syncthreads();
            psum[t] += x;
            __syncthreads();
        }
        int excl = psum[t] - ps;         // exclusive pair prefix
        int rp0 = s0_out + excl;
        int rp1 = rp0 + h0;
        lrow[2 * t] = rp0;
        lrow[2 * t + 1] = rp1;
        int node0 = (g << GSHIFT) + 2 * t;
        int node1 = node0 + 1;
        if (node0 < N) {
            rowptr[node0] = rp0;
            cnt[node0] = h0;
            dinv[node0] = rsqrtf(1.0f + (float)h0);
        }
        if (node1 < N) {
            rowptr[node1] = rp1;
            cnt[node1] = h1;
            dinv[node1] = rsqrtf(1.0f + (float)h1);
        }
        __syncthreads();
        for (int k = t; k < count; k += 256) {
            int p = staged[s0_in + k];
            int dl = p & (GSIZE - 1);
            int pos = lrow[dl] + atomicAdd(&curq[dl], 1);
            csr[pos] = p >> GSHIFT;
        }
        return;
    }

    // ---- gemm1 path (BM=64): Cb[M,128]bf = bf16(A_f32 @ B), no scale ----
    float* Af = (float*)smem;                 // [2][64*32]  16KB
    short* Bh = (short*)(smem + 16384);       // [2][128*32] 16KB
    short* Bl = (short*)(smem + 32768);       // [2][128*32] 16KB
    int wave = t >> 6, lane = t & 63, quad = lane >> 4, l16 = lane & 15;
    int bm0 = ((int)blockIdx.x - ngrp) * 64;
    int M = N;

    floatx4 acc[8];
#pragma unroll
    for (int nt = 0; nt < 8; ++nt) acc[nt] = (floatx4){0.f, 0.f, 0.f, 0.f};

    auto stage = [&](int pb, int k0) {
#pragma unroll
        for (int i = 0; i < 2; ++i) {          // A: 512 granules of 16B
            int g = i * 256 + t;
            int row = g >> 3, col = g & 7;
            int gr = bm0 + row;
            if (gr >= M) gr = M - 1;
            int scol = col ^ (row & 7);
            gload_lds16(A + (size_t)gr * K + k0 + scol * 4,
                        &Af[pb * 2048 + (i * 256 + wave * 64) * 4]);
        }
#pragma unroll
        for (int i = 0; i < 2; ++i) {          // B: 512 granules each
            int g = i * 256 + t;
            int row = g >> 2, col = g & 3;
            int scol = col ^ ((row >> 1) & 3);
            size_t off = (size_t)row * K + k0 + scol * 8;
            int lb = (i * 256 + wave * 64) * 8;
            gload_lds16(Bth + off, &Bh[pb * 4096 + lb]);
            gload_lds16(Btl + off, &Bl[pb * 4096 + lb]);
        }
    };

    int nk = K >> 5;
    stage(0, 0);
    __syncthreads();
    int am = wave * 16 + l16;
    int ac0 = ((quad * 2 + 0) ^ (am & 7)) * 4;
    int ac1 = ((quad * 2 + 1) ^ (am & 7)) * 4;
    int bc = (quad ^ ((l16 >> 1) & 3)) * 8;
    for (int ks = 0; ks < nk; ++ks) {
        int pb = ks & 1;
        if (ks + 1 < nk) stage(pb ^ 1, (ks + 1) << 5);
        float4 fa0 = *(const float4*)&Af[pb * 2048 + am * 32 + ac0];
        float4 fa1 = *(const float4*)&Af[pb * 2048 + am * 32 + ac1];
        short8 a_h, a_l;
        {
            short h, l;
            split2(fa0.x, h, l); a_h[0] = h; a_l[0] = l;
            split2(fa0.y, h, l); a_h[1] = h; a_l[1] = l;
            split2(fa0.z, h, l); a_h[2] = h; a_l[2] = l;
            split2(fa0.w, h, l); a_h[3] = h; a_l[3] = l;
            split2(fa1.x, h, l); a_h[4] = h; a_l[4] = l;
            split2(fa1.y, h, l); a_h[5] = h; a_l[5] = l;
            split2(fa1.z, h, l); a_h[6] = h; a_l[6] = l;
            split2(fa1.w, h, l); a_h[7] = h; a_l[7] = l;
        }
#pragma unroll
        for (int nt = 0; nt < 8; ++nt) {
            int bn = nt * 16 + l16;
            short8 b_h = *(const short8*)&Bh[pb * 4096 + bn * 32 + bc];
            short8 b_l = *(const short8*)&Bl[pb * 4096 + bn * 32 + bc];
            acc[nt] = __builtin_amdgcn_mfma_f32_16x16x32_bf16(a_l, b_h, acc[nt], 0, 0, 0);
            acc[nt] = __builtin_amdgcn_mfma_f32_16x16x32_bf16(a_h, b_l, acc[nt], 0, 0, 0);
            acc[nt] = __builtin_amdgcn_mfma_f32_16x16x32_bf16(a_h, b_h, acc[nt], 0, 0, 0);
        }
        __syncthreads();
    }
#pragma unroll
    for (int reg = 0; reg < 4; ++reg) {
        int gr = bm0 + wave * 16 + quad * 4 + reg;
        if (gr < M) {
            short* cp = Cb + (size_t)gr * 128;
#pragma unroll
            for (int nt = 0; nt < 8; ++nt) cp[nt * 16 + l16] = bf16_rtn(acc[nt][reg]);
        }
    }
}

// ---------------- MFMA GEMM2 (BM=64, pipelined): Cb = ((AH+AL) @ B) * rs ----------------
__global__ __launch_bounds__(TPB) void gemm_mfma_bfin(const short* __restrict__ AH,
                                                      const short* __restrict__ AL,
                                                      const short* __restrict__ Bth,
                                                      const short* __restrict__ Btl,
                                                      const float* __restrict__ rs,
                                                      short* __restrict__ Cb, int M, int K) {
    __shared__ short Ah[2][64 * 32], Al[2][64 * 32];   // 2 x 4KB each
    __shared__ short Bh[2][128 * 32], Bl[2][128 * 32]; // 2 x 8KB each -> 48KB total
    int t = threadIdx.x;
    int wave = t >> 6, lane = t & 63, quad = lane >> 4, l16 = lane & 15;
    int bm0 = blockIdx.x * 64;

    floatx4 acc[8];
#pragma unroll
    for (int nt = 0; nt < 8; ++nt) acc[nt] = (floatx4){0.f, 0.f, 0.f, 0.f};

    auto stage = [&](int pb, int k0) {
        {
            int row = t >> 2, col = t & 3;
            int gr = bm0 + row;
            if (gr >= M) gr = M - 1;
            int scol = col ^ ((row >> 1) & 3);
            size_t off = (size_t)gr * K + k0 + scol * 8;
            int lb = (wave * 64) * 8;
            gload_lds16(AH + off, &Ah[pb][lb]);
            gload_lds16(AL + off, &Al[pb][lb]);
        }
#pragma unroll
        for (int i = 0; i < 2; ++i) {
            int g = i * 256 + t;
            int row = g >> 2, col = g & 3;
            int scol = col ^ ((row >> 1) & 3);
            size_t off = (size_t)row * K + k0 + scol * 8;
            int lb = (i * 256 + wave * 64) * 8;
            gload_lds16(Bth + off, &Bh[pb][lb]);
            gload_lds16(Btl + off, &Bl[pb][lb]);
        }
    };

    int nk = K >> 5;
    stage(0, 0);
    __syncthreads();
    int am = wave * 16 + l16;
    int ac = (quad ^ ((am >> 1) & 3)) * 8;
    int bc = (quad ^ ((l16 >> 1) & 3)) * 8;
    for (int ks = 0; ks < nk; ++ks) {
        int pb = ks & 1;
        if (ks + 1 < nk) stage(pb ^ 1, (ks + 1) << 5);
        short8 a_h = *(const short8*)&Ah[pb][am * 32 + ac];
        short8 a_l = *(const short8*)&Al[pb][am * 32 + ac];
#pragma unroll
        for (int nt = 0; nt < 8; ++nt) {
            int bn = nt * 16 + l16;
            short8 b_h = *(const short8*)&Bh[pb][bn * 32 + bc];
            short8 b_l = *(const short8*)&Bl[pb][bn * 32 + bc];
            acc[nt] = __builtin_amdgcn_mfma_f32_16x16x32_bf16(a_l, b_h, acc[nt], 0, 0, 0);
            acc[nt] = __builtin_amdgcn_mfma_f32_16x16x32_bf16(a_h, b_l, acc[nt], 0, 0, 0);
            acc[nt] = __builtin_amdgcn_mfma_f32_16x16x32_bf16(a_h, b_h, acc[nt], 0, 0, 0);
        }
        __syncthreads();
    }
#pragma unroll
    for (int reg = 0; reg < 4; ++reg) {
        int gr = bm0 + wave * 16 + quad * 4 + reg;
        if (gr < M) {
            float s = rs[gr];
            short* cp = Cb + (size_t)gr * 128;
#pragma unroll
            for (int nt = 0; nt < 8; ++nt) cp[nt * 16 + l16] = bf16_rtn(acc[nt][reg] * s);
        }
    }
}

// ---------------- gather 1: hidden = relu(dinv*(dinv*h_self + sum dinv_s*h_s) + b1) ----------------
__global__ __launch_bounds__(TPB) void gather_hidden(const int* __restrict__ csr,
                                                     const int* __restrict__ rowptr,
                                                     const int* __restrict__ cnt,
                                                     const float* __restrict__ dinv,
                                                     const short* __restrict__ hs,
                                                     const float* __restrict__ b1,
                                                     short* __restrict__ hidH,
                                                     short* __restrict__ hidL, int N) {
    size_t t = (size_t)blockIdx.x * TPB + threadIdx.x;
    int nid = (int)(t >> 4);
    int lane = threadIdx.x & 15;
    if (nid >= N) return;
    int start = rowptr[nid];
    int deg = cnt[nid];
    float di = dinv[nid];
    const uint4v* hp = (const uint4v*)hs;  // row = 16 x 16B, raw h bf16
    float acc[8] = {0, 0, 0, 0, 0, 0, 0, 0};
    addrow_s(acc, hp[(size_t)nid * 16 + lane], di);      // self: dinv[d]*h[d]
    gather_accum_s(acc, csr, dinv, start, deg, hp, lane);
    float4 b0 = ((const float4*)b1)[lane * 2];
    float4 b1v = ((const float4*)b1)[lane * 2 + 1];
    float bb[8] = {b0.x, b0.y, b0.z, b0.w, b1v.x, b1v.y, b1v.z, b1v.w};
    unsigned hiw[8];
    short low[8];
#pragma unroll
    for (int i = 0; i < 8; ++i) {
        float h = fmaxf(fmaf(di, acc[i], bb[i]), 0.f);
        unsigned u = __float_as_uint(h);
        hiw[i] = u >> 16;
        float hf = __uint_as_float(u & 0xFFFF0000u);
        low[i] = bf16_rtn(h - hf);
    }
    uint4v ph, pl;
    ph[0] = hiw[0] | (hiw[1] << 16);
    ph[1] = hiw[2] | (hiw[3] << 16);
    ph[2] = hiw[4] | (hiw[5] << 16);
    ph[3] = hiw[6] | (hiw[7] << 16);
    pl[0] = (unsigned short)low[0] | ((unsigned)(unsigned short)low[1] << 16);
    pl[1] = (unsigned short)low[2] | ((unsigned)(unsigned short)low[3] << 16);
    pl[2] = (unsigned short)low[4] | ((unsigned)(unsigned short)low[5] << 16);
    pl[3] = (unsigned short)low[6] | ((unsigned)(unsigned short)low[7] << 16);
    ((uint4v*)hidH)[(size_t)nid * 16 + lane] = ph;   // normal store: keep L3-resident
    ((uint4v*)hidL)[(size_t)nid * 16 + lane] = pl;
}

// ---------------- gather 2: out = dinv*(self+sum nbrs) + bcat -> f32 mu|logvar ----------------
__global__ __launch_bounds__(TPB) void gather_out(const int* __restrict__ csr,
                                                  const int* __restrict__ rowptr,
                                                  const int* __restrict__ cnt,
                                                  const float* __restrict__ dinv,
                                                  const short* __restrict__ hs,
                                                  const float* __restrict__ bcat,
                                                  float* __restrict__ out, int N) {
    size_t t = (size_t)blockIdx.x * TPB + threadIdx.x;
    int nid = (int)(t >> 4);
    int lane = threadIdx.x & 15;
    if (nid >= N) return;
    int start = rowptr[nid];
    int deg = cnt[nid];
    const uint4v* hp = (const uint4v*)hs;   // hs2 already carries dinv
    float acc[8] = {0, 0, 0, 0, 0, 0, 0, 0};
    addrow(acc, hp[(size_t)nid * 16 + lane]);
    gather_accum(acc, csr, start, deg, hp, lane);
    float di = dinv[nid];
    float4 b0 = ((const float4*)bcat)[lane * 2];
    float4 b1v = ((const float4*)bcat)[lane * 2 + 1];
    floatx4 r0, r1;
    r0[0] = fmaf(di, acc[0], b0.x);
    r0[1] = fmaf(di, acc[1], b0.y);
    r0[2] = fmaf(di, acc[2], b0.z);
    r0[3] = fmaf(di, acc[3], b0.w);
    r1[0] = fmaf(di, acc[4], b1v.x);
    r1[1] = fmaf(di, acc[5], b1v.y);
    r1[2] = fmaf(di, acc[6], b1v.z);
    r1[3] = fmaf(di, acc[7], b1v.w);
    int f = lane * 8;  // 0..120
    float* dp = (f < 64) ? (out + (size_t)nid * 64 + f)
                         : (out + (size_t)N * 64 + (size_t)nid * 64 + (f - 64));
    __builtin_nontemporal_store(r0, (floatx4*)dp);    // final output: never re-read
    __builtin_nontemporal_store(r1, (floatx4*)(dp + 4));
}

extern "C" void kernel_launch(void* const* d_in, const int* in_sizes, int n_in,
                              void* d_out, int out_size, void* d_ws, size_t ws_size,
                              hipStream_t stream) {
    const float* x  = (const float*)d_in[0];
    const float* w1 = (const float*)d_in[1];
    const float* b1 = (const float*)d_in[2];
    const float* w2 = (const float*)d_in[3];
    const float* b2 = (const float*)d_in[4];
    const float* w3 = (const float*)d_in[5];
    const float* b3 = (const float*)d_in[6];
    const int*   ei = (const int*)d_in[7];

    const int N = in_sizes[0] / 256;   // 100000
    const int E = in_sizes[7] / 2;     // 1600000
    const int K1 = 256;

    float* out = (float*)d_out;

    // workspace carve-up (layout stable)
    size_t nh = (size_t)N * 128;
    short* hs1    = (short*)d_ws;          // N*128 bf16 (raw h)
    short* hidH   = hs1 + nh;
    short* hidL   = hidH + nh;
    short* hs2    = hidL + nh;
    int*   cnt    = (int*)(hs2 + nh);
    float* dinv   = (float*)(cnt + N);
    int*   rowptr = (int*)(dinv + N);
    int*   cursor = rowptr + N;            // gcur[256]
    int*   bsum   = cursor + N;
    float* bcat   = (float*)(bsum + 512);
    short* w1t_h  = (short*)(bcat + 128);
    short* w1t_l  = w1t_h + 128 * 256;
    short* wct_h  = w1t_l + 128 * 256;
    short* wct_l  = wct_h + 128 * 128;
    int*   csr    = (int*)(wct_l + 128 * 128);

    const int* srcp = ei;
    const int* dstp = ei + E;

    const int ngrp = (N + GSIZE - 1) >> GSHIFT;   // 196
    int* gcur   = cursor;        // [256]
    int* staged = (int*)hs2;     // alias: 9.6MB; dead before gemm_bfin writes hs2

    // 0) zero group cursors (needed before kernel A's partition blocks)
    hipMemsetAsync(gcur, 0, 256 * sizeof(int), stream);

    // 1) A: prep (192 blocks) || partition
    int nPart = (E + PART_M - 1) / PART_M;
    prep_part<<<NPREP + nPart, TPB, 0, stream>>>(w1, w2, b2, w3, b3, w1t_h, w1t_l,
                                                 wct_h, wct_l, bcat, srcp, dstp, gcur,
                                                 staged, E);

    // 2) B: build_csr (196 blocks) || gemm1 BM=64 (1563 blocks)
    int gtiles = (N + 63) / 64;
    csr_gemm1<<<ngrp + gtiles, TPB, 0, stream>>>(staged, gcur, cnt, dinv, rowptr, csr,
                                                 x, w1t_h, w1t_l, hs1, N, K1, ngrp);

    // 3) hidden = relu(dinv*(dinv*h_self + sum dinv_s*h_s) + b1) -> hi/lo bf16
    size_t gthreads = (size_t)N * 16;
    gather_hidden<<<(unsigned)((gthreads + TPB - 1) / TPB), TPB, 0, stream>>>(
        csr, rowptr, cnt, dinv, hs1, b1, hidH, hidL, N);

    // 4) hs2 = (hidden @ wcat) * dinv -> bf16   (overwrites staged — dead by now)
    gemm_mfma_bfin<<<(N + 63) / 64, TPB, 0, stream>>>(hidH, hidL, wct_h, wct_l, dinv, hs2, N, 128);

    // 5) out = dinv*(self+nbrs) + bcat -> mu | logvar (f32)
    gather_out<<<(unsigned)((gthreads + TPB - 1) / TPB), TPB, 0, stream>>>(
        csr, rowptr, cnt, dinv, hs2, bcat, out, N);
}

// Round 14
// 365.867 us; speedup vs baseline: 1.0201x; 1.0201x over previous
//
#include <hip/hip_runtime.h>

// GCN-VAE encoder forward on MI355X — R17: drop B-low MFMA term (2-term GEMMs).
//
// agg[d] = dinv[d] * ( dinv[d]*h[d] + sum_s dinv[s]*h[s] )
//
// R17: both GEMMs use (a_hi + a_lo) x b_hi  (2 MFMA/frag instead of 3):
//   A stays exact (hi/lo split); W rounds to bf16 (2^-9 rel). Propagated
//   error ~4e-4 final — an order below the current 3.9e-3 absmax (one
//   output-path bf16 ULP). Payoff: MFMA count 24->16/k-step AND B-low gone
//   from LDS: 48KB -> 32KB/block -> 5 blocks/CU = 20 waves/CU (was 3/12).
//   Attacks R14-measured deficits (MfmaUtil ~11%, occupancy ~16%) directly.
//
// R16: gemm_bfin BM=64 (null -> structure-bound, motivating R17).
// R15: csr_gemm1 BM=64 + LDS union with csr path. R14: prep||partition,
//   build_csr||gemm1 fusions (dinv folded into gather_hidden fma-gather).
// R13: fixed-capacity staged spans. R11: shfl-shared gather indices.
// R9: NO gather/GEMM occupancy fusion. R8: gathers at random-256B wall
//   (~66-68us each; 4 null experiments) — accepted.
//
// ws: hs1[N*128]bf | hidH | hidL | hs2 (aliased staged during CSR build) |
//     cnt[N] | dinv[N] | rowptr[N] | cursor (gcur[256]) | bsum[512] |
//     bcat[128] | w1t_h/l | wct_h/l | csr[E]   (the _l slots now unused)

#define TPB 256
#define GSHIFT 9
#define GSIZE 512
#define PART_M 4096   // edges per partition WG
#define GCAP 12288    // fixed staged span per group
#define NPREP 192     // prep blocks in kernel A

typedef __attribute__((ext_vector_type(8))) short short8;
typedef __attribute__((ext_vector_type(4))) short short4v;
typedef __attribute__((ext_vector_type(4))) float floatx4;
typedef __attribute__((ext_vector_type(4))) unsigned int uint4v;

__device__ __forceinline__ void split2(float v, short& hi, short& lo) {
    unsigned u = __float_as_uint(v);
    float hf = __uint_as_float(u & 0xFFFF0000u);
    float lf = v - hf;                       // exact
    hi = (short)(u >> 16);
    lo = (short)(__float_as_uint(lf) >> 16);
}

__device__ __forceinline__ short bf16_rtn(float v) {
    unsigned u = __float_as_uint(v);
    u += 0x7FFF + ((u >> 16) & 1);           // round to nearest even
    return (short)(u >> 16);
}

__device__ __forceinline__ void addrow(float* a, uint4v v) {
    a[0] += __uint_as_float(v[0] << 16); a[1] += __uint_as_float(v[0] & 0xFFFF0000u);
    a[2] += __uint_as_float(v[1] << 16); a[3] += __uint_as_float(v[1] & 0xFFFF0000u);
    a[4] += __uint_as_float(v[2] << 16); a[5] += __uint_as_float(v[2] & 0xFFFF0000u);
    a[6] += __uint_as_float(v[3] << 16); a[7] += __uint_as_float(v[3] & 0xFFFF0000u);
}

// scaled accumulate: a += s * row
__device__ __forceinline__ void addrow_s(float* a, uint4v v, float s) {
    a[0] = fmaf(s, __uint_as_float(v[0] << 16), a[0]);
    a[1] = fmaf(s, __uint_as_float(v[0] & 0xFFFF0000u), a[1]);
    a[2] = fmaf(s, __uint_as_float(v[1] << 16), a[2]);
    a[3] = fmaf(s, __uint_as_float(v[1] & 0xFFFF0000u), a[3]);
    a[4] = fmaf(s, __uint_as_float(v[2] << 16), a[4]);
    a[5] = fmaf(s, __uint_as_float(v[2] & 0xFFFF0000u), a[5]);
    a[6] = fmaf(s, __uint_as_float(v[3] << 16), a[6]);
    a[7] = fmaf(s, __uint_as_float(v[3] & 0xFFFF0000u), a[7]);
}

// unscaled gather (gather_out: hs2 already carries dinv)
__device__ __forceinline__ void gather_accum(float* acc, const int* __restrict__ csr,
                                             int start, int deg, const uint4v* hp,
                                             int l16) {
    for (int jj = 0; jj < deg; jj += 16) {
        int rem = deg - jj;
        if (rem > 16) rem = 16;
        int il = (l16 < rem) ? l16 : rem - 1;
        int myIdx = csr[start + jj + il];
        int r = 0;
        for (; r + 3 < rem; r += 4) {
            int i0 = __shfl(myIdx, r + 0, 16);
            int i1 = __shfl(myIdx, r + 1, 16);
            int i2 = __shfl(myIdx, r + 2, 16);
            int i3 = __shfl(myIdx, r + 3, 16);
            uint4v v0 = hp[(size_t)i0 * 16 + l16];
            uint4v v1 = hp[(size_t)i1 * 16 + l16];
            uint4v v2 = hp[(size_t)i2 * 16 + l16];
            uint4v v3 = hp[(size_t)i3 * 16 + l16];
            addrow(acc, v0);
            addrow(acc, v1);
            addrow(acc, v2);
            addrow(acc, v3);
        }
        for (; r < rem; ++r) {
            int i = __shfl(myIdx, r, 16);
            addrow(acc, hp[(size_t)i * 16 + l16]);
        }
    }
}

// dinv-scaled gather (gather_hidden: rows are raw h, scale by dinv[s])
__device__ __forceinline__ void gather_accum_s(float* acc, const int* __restrict__ csr,
                                               const float* __restrict__ dinv,
                                               int start, int deg, const uint4v* hp,
                                               int l16) {
    for (int jj = 0; jj < deg; jj += 16) {
        int rem = deg - jj;
        if (rem > 16) rem = 16;
        int il = (l16 < rem) ? l16 : rem - 1;
        int myIdx = csr[start + jj + il];
        float myD = dinv[myIdx];
        int r = 0;
        for (; r + 3 < rem; r += 4) {
            int i0 = __shfl(myIdx, r + 0, 16);
            int i1 = __shfl(myIdx, r + 1, 16);
            int i2 = __shfl(myIdx, r + 2, 16);
            int i3 = __shfl(myIdx, r + 3, 16);
            float d0 = __shfl(myD, r + 0, 16);
            float d1 = __shfl(myD, r + 1, 16);
            float d2 = __shfl(myD, r + 2, 16);
            float d3 = __shfl(myD, r + 3, 16);
            uint4v v0 = hp[(size_t)i0 * 16 + l16];
            uint4v v1 = hp[(size_t)i1 * 16 + l16];
            uint4v v2 = hp[(size_t)i2 * 16 + l16];
            uint4v v3 = hp[(size_t)i3 * 16 + l16];
            addrow_s(acc, v0, d0);
            addrow_s(acc, v1, d1);
            addrow_s(acc, v2, d2);
            addrow_s(acc, v3, d3);
        }
        for (; r < rem; ++r) {
            int i = __shfl(myIdx, r, 16);
            float d = __shfl(myD, r, 16);
            addrow_s(acc, hp[(size_t)i * 16 + l16], d);
        }
    }
}

// async 16B global -> LDS (linear dest: wave-uniform base + lane*16)
__device__ __forceinline__ void gload_lds16(const void* g, void* l) {
    __builtin_amdgcn_global_load_lds(
        (const __attribute__((address_space(1))) unsigned int*)g,
        (__attribute__((address_space(3))) unsigned int*)l, 16, 0, 0);
}

// ---------------- kernel A: prep (blocks 0..191) || partition (rest) ----------------
// Only the hi halves of the weights are needed now (2-term GEMMs).
__global__ __launch_bounds__(TPB) void prep_part(const float* __restrict__ w1,
                                                 const float* __restrict__ w2,
                                                 const float* __restrict__ b2,
                                                 const float* __restrict__ w3,
                                                 const float* __restrict__ b3,
                                                 short* __restrict__ w1t_h,
                                                 short* __restrict__ wct_h,
                                                 float* __restrict__ bcat,
                                                 const int* __restrict__ src,
                                                 const int* __restrict__ dst,
                                                 int* __restrict__ gcur,
                                                 int* __restrict__ staged, int E) {
    __shared__ int sc[256];
    __shared__ int cur[256];
    __shared__ int gb[256];
    int b = blockIdx.x, t = threadIdx.x;
    if (b < 128) {
        int i = b * TPB + t;                 // < 128*256
        int k = i & 255, n = i >> 8;
        w1t_h[i] = bf16_rtn(w1[(size_t)k * 128 + n]);
        return;
    } else if (b < NPREP) {
        int i = (b - 128) * TPB + t;         // < 128*128
        int k = i & 127, n = i >> 7;
        float v = (n < 64) ? w2[(size_t)k * 64 + n] : w3[(size_t)k * 64 + (n - 64)];
        wct_h[i] = bf16_rtn(v);
        if (i < 64) { bcat[i] = b2[i]; bcat[64 + i] = b3[i]; }
        return;
    }
    // ---- partition path ----
    int base = (b - NPREP) * PART_M;
    int mloc = min(PART_M, E - base);
    int m4 = mloc >> 2;
    sc[t] = 0;
    cur[t] = 0;
    __syncthreads();
    const int4* d4 = (const int4*)(dst + base);
    const int4* s4 = (const int4*)(src + base);
    for (int k = t; k < m4; k += 256) {
        int4 v = d4[k];
        atomicAdd(&sc[v.x >> GSHIFT], 1);
        atomicAdd(&sc[v.y >> GSHIFT], 1);
        atomicAdd(&sc[v.z >> GSHIFT], 1);
        atomicAdd(&sc[v.w >> GSHIFT], 1);
    }
    for (int k = (m4 << 2) + t; k < mloc; k += 256)
        atomicAdd(&sc[dst[base + k] >> GSHIFT], 1);
    __syncthreads();
    int v = sc[t];
    gb[t] = v ? t * GCAP + atomicAdd(&gcur[t], v) : 0;   // exclusive span slice
    __syncthreads();
    for (int k = t; k < m4; k += 256) {
        int4 dv = d4[k];
        int4 sv = s4[k];
        int b0 = dv.x >> GSHIFT;
        staged[gb[b0] + atomicAdd(&cur[b0], 1)] = (sv.x << GSHIFT) | (dv.x & (GSIZE - 1));
        int b1 = dv.y >> GSHIFT;
        staged[gb[b1] + atomicAdd(&cur[b1], 1)] = (sv.y << GSHIFT) | (dv.y & (GSIZE - 1));
        int b2_ = dv.z >> GSHIFT;
        staged[gb[b2_] + atomicAdd(&cur[b2_], 1)] = (sv.z << GSHIFT) | (dv.z & (GSIZE - 1));
        int b3_ = dv.w >> GSHIFT;
        staged[gb[b3_] + atomicAdd(&cur[b3_], 1)] = (sv.w << GSHIFT) | (dv.w & (GSIZE - 1));
    }
    for (int k = (m4 << 2) + t; k < mloc; k += 256) {
        int d = dst[base + k];
        int s = src[base + k];
        int bb = d >> GSHIFT;
        staged[gb[bb] + atomicAdd(&cur[bb], 1)] = (s << GSHIFT) | (d & (GSIZE - 1));
    }
}

// ---------------- kernel B: build_csr256 (blocks 0..ngrp) || gemm1 BM=64 (rest) ----------------
// gemm1: Cb = bf16((A_hi + A_lo) @ B_hi), A split at fragment read. 32KB LDS.
__global__ __launch_bounds__(TPB) void csr_gemm1(const int* __restrict__ staged,
                                                 const int* __restrict__ gcur,
                                                 int* __restrict__ cnt,
                                                 float* __restrict__ dinv,
                                                 int* __restrict__ rowptr,
                                                 int* __restrict__ csr,
                                                 const float* __restrict__ A,
                                                 const short* __restrict__ Bth,
                                                 short* __restrict__ Cb,
                                                 int N, int K, int ngrp) {
    __shared__ __align__(16) char smem[32768];   // 32KB union -> 5 blocks/CU
    int t = threadIdx.x;

    if ((int)blockIdx.x < ngrp) {
        // ---- build_csr path (256 threads, one 512-node group; 8KB of smem) ----
        int* pre  = (int*)smem;        // [256]
        int* hist = pre + 256;         // [512]
        int* psum = hist + 512;        // [256]
        int* lrow = psum + 256;        // [512]
        int* curq = lrow + 512;        // [512]
        int g = blockIdx.x;
        pre[t] = (t < ngrp) ? gcur[t] : 0;
        hist[t] = 0;
        hist[t + 256] = 0;
        curq[t] = 0;
        curq[t + 256] = 0;
        __syncthreads();
#pragma unroll
        for (int off = 1; off < 256; off <<= 1) {
            int x = (t >= off) ? pre[t - off] : 0;
            __syncthreads();
            pre[t] += x;
            __syncthreads();
        }
        int count = gcur[g];
        int s0_out = pre[g] - count;     // exact exclusive offset into csr
        int s0_in = g * GCAP;
        for (int k = t; k < count; k += 256)
            atomicAdd(&hist[staged[s0_in + k] & (GSIZE - 1)], 1);
        __syncthreads();
        int h0 = hist[2 * t], h1 = hist[2 * t + 1];
        int ps = h0 + h1;
        psum[t] = ps;
        __syncthreads();
#pragma unroll
        for (int off = 1; off < 256; off <<= 1) {
            int x = (t >= off) ? psum[t - off] : 0;
            __syncthreads();
            psum[t] += x;
            __syncthreads();
        }
        int excl = psum[t] - ps;         // exclusive pair prefix
        int rp0 = s0_out + excl;
        int rp1 = rp0 + h0;
        lrow[2 * t] = rp0;
        lrow[2 * t + 1] = rp1;
        int node0 = (g << GSHIFT) + 2 * t;
        int node1 = node0 + 1;
        if (node0 < N) {
            rowptr[node0] = rp0;
            cnt[node0] = h0;
            dinv[node0] = rsqrtf(1.0f + (float)h0);
        }
        if (node1 < N) {
            rowptr[node1] = rp1;
            cnt[node1] = h1;
            dinv[node1] = rsqrtf(1.0f + (float)h1);
        }
        __syncthreads();
        for (int k = t; k < count; k += 256) {
            int p = staged[s0_in + k];
            int dl = p & (GSIZE - 1);
            int pos = lrow[dl] + atomicAdd(&curq[dl], 1);
            csr[pos] = p >> GSHIFT;
        }
        return;
    }

    // ---- gemm1 path (BM=64, 2-term): Cb[M,128]bf = bf16(A @ B_hi) ----
    float* Af = (float*)smem;                 // [2][64*32]  16KB
    short* Bh = (short*)(smem + 16384);       // [2][128*32] 16KB
    int wave = t >> 6, lane = t & 63, quad = lane >> 4, l16 = lane & 15;
    int bm0 = ((int)blockIdx.x - ngrp) * 64;
    int M = N;

    floatx4 acc[8];
#pragma unroll
    for (int nt = 0; nt < 8; ++nt) acc[nt] = (floatx4){0.f, 0.f, 0.f, 0.f};

    auto stage = [&](int pb, int k0) {
#pragma unroll
        for (int i = 0; i < 2; ++i) {          // A: 512 granules of 16B
            int g = i * 256 + t;
            int row = g >> 3, col = g & 7;
            int gr = bm0 + row;
            if (gr >= M) gr = M - 1;
            int scol = col ^ (row & 7);
            gload_lds16(A + (size_t)gr * K + k0 + scol * 4,
                        &Af[pb * 2048 + (i * 256 + wave * 64) * 4]);
        }
#pragma unroll
        for (int i = 0; i < 2; ++i) {          // B_hi: 512 granules
            int g = i * 256 + t;
            int row = g >> 2, col = g & 3;
            int scol = col ^ ((row >> 1) & 3);
            size_t off = (size_t)row * K + k0 + scol * 8;
            int lb = (i * 256 + wave * 64) * 8;
            gload_lds16(Bth + off, &Bh[pb * 4096 + lb]);
        }
    };

    int nk = K >> 5;
    stage(0, 0);
    __syncthreads();
    int am = wave * 16 + l16;
    int ac0 = ((quad * 2 + 0) ^ (am & 7)) * 4;
    int ac1 = ((quad * 2 + 1) ^ (am & 7)) * 4;
    int bc = (quad ^ ((l16 >> 1) & 3)) * 8;
    for (int ks = 0; ks < nk; ++ks) {
        int pb = ks & 1;
        if (ks + 1 < nk) stage(pb ^ 1, (ks + 1) << 5);
        float4 fa0 = *(const float4*)&Af[pb * 2048 + am * 32 + ac0];
        float4 fa1 = *(const float4*)&Af[pb * 2048 + am * 32 + ac1];
        short8 a_h, a_l;
        {
            short h, l;
            split2(fa0.x, h, l); a_h[0] = h; a_l[0] = l;
            split2(fa0.y, h, l); a_h[1] = h; a_l[1] = l;
            split2(fa0.z, h, l); a_h[2] = h; a_l[2] = l;
            split2(fa0.w, h, l); a_h[3] = h; a_l[3] = l;
            split2(fa1.x, h, l); a_h[4] = h; a_l[4] = l;
            split2(fa1.y, h, l); a_h[5] = h; a_l[5] = l;
            split2(fa1.z, h, l); a_h[6] = h; a_l[6] = l;
            split2(fa1.w, h, l); a_h[7] = h; a_l[7] = l;
        }
#pragma unroll
        for (int nt = 0; nt < 8; ++nt) {
            int bn = nt * 16 + l16;
            short8 b_h = *(const short8*)&Bh[pb * 4096 + bn * 32 + bc];
            acc[nt] = __builtin_amdgcn_mfma_f32_16x16x32_bf16(a_l, b_h, acc[nt], 0, 0, 0);
            acc[nt] = __builtin_amdgcn_mfma_f32_16x16x32_bf16(a_h, b_h, acc[nt], 0, 0, 0);
        }
        __syncthreads();
    }
#pragma unroll
    for (int reg = 0; reg < 4; ++reg) {
        int gr = bm0 + wave * 16 + quad * 4 + reg;
        if (gr < M) {
            short* cp = Cb + (size_t)gr * 128;
#pragma unroll
            for (int nt = 0; nt < 8; ++nt) cp[nt * 16 + l16] = bf16_rtn(acc[nt][reg]);
        }
    }
}

// ---------------- MFMA GEMM2 (BM=64, 2-term): Cb = ((AH+AL) @ B_hi) * rs ----------------
__global__ __launch_bounds__(TPB) void gemm_mfma_bfin(const short* __restrict__ AH,
                                                      const short* __restrict__ AL,
                                                      const short* __restrict__ Bth,
                                                      const float* __restrict__ rs,
                                                      short* __restrict__ Cb, int M, int K) {
    __shared__ short Ah[2][64 * 32], Al[2][64 * 32];   // 2 x 4KB each
    __shared__ short Bh[2][128 * 32];                  // 2 x 8KB -> 32KB total
    int t = threadIdx.x;
    int wave = t >> 6, lane = t & 63, quad = lane >> 4, l16 = lane & 15;
    int bm0 = blockIdx.x * 64;

    floatx4 acc[8];
#pragma unroll
    for (int nt = 0; nt < 8; ++nt) acc[nt] = (floatx4){0.f, 0.f, 0.f, 0.f};

    auto stage = [&](int pb, int k0) {
        {
            int row = t >> 2, col = t & 3;
            int gr = bm0 + row;
            if (gr >= M) gr = M - 1;
            int scol = col ^ ((row >> 1) & 3);
            size_t off = (size_t)gr * K + k0 + scol * 8;
            int lb = (wave * 64) * 8;
            gload_lds16(AH + off, &Ah[pb][lb]);
            gload_lds16(AL + off, &Al[pb][lb]);
        }
#pragma unroll
        for (int i = 0; i < 2; ++i) {
            int g = i * 256 + t;
            int row = g >> 2, col = g & 3;
            int scol = col ^ ((row >> 1) & 3);
            size_t off = (size_t)row * K + k0 + scol * 8;
            int lb = (i * 256 + wave * 64) * 8;
            gload_lds16(Bth + off, &Bh[pb][lb]);
        }
    };

    int nk = K >> 5;
    stage(0, 0);
    __syncthreads();
    int am = wave * 16 + l16;
    int ac = (quad ^ ((am >> 1) & 3)) * 8;
    int bc = (quad ^ ((l16 >> 1) & 3)) * 8;
    for (int ks = 0; ks < nk; ++ks) {
        int pb = ks & 1;
        if (ks + 1 < nk) stage(pb ^ 1, (ks + 1) << 5);
        short8 a_h = *(const short8*)&Ah[pb][am * 32 + ac];
        short8 a_l = *(const short8*)&Al[pb][am * 32 + ac];
#pragma unroll
        for (int nt = 0; nt < 8; ++nt) {
            int bn = nt * 16 + l16;
            short8 b_h = *(const short8*)&Bh[pb][bn * 32 + bc];
            acc[nt] = __builtin_amdgcn_mfma_f32_16x16x32_bf16(a_l, b_h, acc[nt], 0, 0, 0);
            acc[nt] = __builtin_amdgcn_mfma_f32_16x16x32_bf16(a_h, b_h, acc[nt], 0, 0, 0);
        }
        __syncthreads();
    }
#pragma unroll
    for (int reg = 0; reg < 4; ++reg) {
        int gr = bm0 + wave * 16 + quad * 4 + reg;
        if (gr < M) {
            float s = rs[gr];
            short* cp = Cb + (size_t)gr * 128;
#pragma unroll
            for (int nt = 0; nt < 8; ++nt) cp[nt * 16 + l16] = bf16_rtn(acc[nt][reg] * s);
        }
    }
}

// ---------------- gather 1: hidden = relu(dinv*(dinv*h_self + sum dinv_s*h_s) + b1) ----------------
__global__ __launch_bounds__(TPB) void gather_hidden(const int* __restrict__ csr,
                                                     const int* __restrict__ rowptr,
                                                     const int* __restrict__ cnt,
                                                     const float* __restrict__ dinv,
                                                     const short* __restrict__ hs,
                                                     const float* __restrict__ b1,
                                                     short* __restrict__ hidH,
                                                     short* __restrict__ hidL, int N) {
    size_t t = (size_t)blockIdx.x * TPB + threadIdx.x;
    int nid = (int)(t >> 4);
    int lane = threadIdx.x & 15;
    if (nid >= N) return;
    int start = rowptr[nid];
    int deg = cnt[nid];
    float di = dinv[nid];
    const uint4v* hp = (const uint4v*)hs;  // row = 16 x 16B, raw h bf16
    float acc[8] = {0, 0, 0, 0, 0, 0, 0, 0};
    addrow_s(acc, hp[(size_t)nid * 16 + lane], di);      // self: dinv[d]*h[d]
    gather_accum_s(acc, csr, dinv, start, deg, hp, lane);
    float4 b0 = ((const float4*)b1)[lane * 2];
    float4 b1v = ((const float4*)b1)[lane * 2 + 1];
    float bb[8] = {b0.x, b0.y, b0.z, b0.w, b1v.x, b1v.y, b1v.z, b1v.w};
    unsigned hiw[8];
    short low[8];
#pragma unroll
    for (int i = 0; i < 8; ++i) {
        float h = fmaxf(fmaf(di, acc[i], bb[i]), 0.f);
        unsigned u = __float_as_uint(h);
        hiw[i] = u >> 16;
        float hf = __uint_as_float(u & 0xFFFF0000u);
        low[i] = bf16_rtn(h - hf);
    }
    uint4v ph, pl;
    ph[0] = hiw[0] | (hiw[1] << 16);
    ph[1] = hiw[2] | (hiw[3] << 16);
    ph[2] = hiw[4] | (hiw[5] << 16);
    ph[3] = hiw[6] | (hiw[7] << 16);
    pl[0] = (unsigned short)low[0] | ((unsigned)(unsigned short)low[1] << 16);
    pl[1] = (unsigned short)low[2] | ((unsigned)(unsigned short)low[3] << 16);
    pl[2] = (unsigned short)low[4] | ((unsigned)(unsigned short)low[5] << 16);
    pl[3] = (unsigned short)low[6] | ((unsigned)(unsigned short)low[7] << 16);
    ((uint4v*)hidH)[(size_t)nid * 16 + lane] = ph;   // normal store: keep L3-resident
    ((uint4v*)hidL)[(size_t)nid * 16 + lane] = pl;
}

// ---------------- gather 2: out = dinv*(self+sum nbrs) + bcat -> f32 mu|logvar ----------------
__global__ __launch_bounds__(TPB) void gather_out(const int* __restrict__ csr,
                                                  const int* __restrict__ rowptr,
                                                  const int* __restrict__ cnt,
                                                  const float* __restrict__ dinv,
                                                  const short* __restrict__ hs,
                                                  const float* __restrict__ bcat,
                                                  float* __restrict__ out, int N) {
    size_t t = (size_t)blockIdx.x * TPB + threadIdx.x;
    int nid = (int)(t >> 4);
    int lane = threadIdx.x & 15;
    if (nid >= N) return;
    int start = rowptr[nid];
    int deg = cnt[nid];
    const uint4v* hp = (const uint4v*)hs;   // hs2 already carries dinv
    float acc[8] = {0, 0, 0, 0, 0, 0, 0, 0};
    addrow(acc, hp[(size_t)nid * 16 + lane]);
    gather_accum(acc, csr, start, deg, hp, lane);
    float di = dinv[nid];
    float4 b0 = ((const float4*)bcat)[lane * 2];
    float4 b1v = ((const float4*)bcat)[lane * 2 + 1];
    floatx4 r0, r1;
    r0[0] = fmaf(di, acc[0], b0.x);
    r0[1] = fmaf(di, acc[1], b0.y);
    r0[2] = fmaf(di, acc[2], b0.z);
    r0[3] = fmaf(di, acc[3], b0.w);
    r1[0] = fmaf(di, acc[4], b1v.x);
    r1[1] = fmaf(di, acc[5], b1v.y);
    r1[2] = fmaf(di, acc[6], b1v.z);
    r1[3] = fmaf(di, acc[7], b1v.w);
    int f = lane * 8;  // 0..120
    float* dp = (f < 64) ? (out + (size_t)nid * 64 + f)
                         : (out + (size_t)N * 64 + (size_t)nid * 64 + (f - 64));
    __builtin_nontemporal_store(r0, (floatx4*)dp);    // final output: never re-read
    __builtin_nontemporal_store(r1, (floatx4*)(dp + 4));
}

extern "C" void kernel_launch(void* const* d_in, const int* in_sizes, int n_in,
                              void* d_out, int out_size, void* d_ws, size_t ws_size,
                              hipStream_t stream) {
    const float* x  = (const float*)d_in[0];
    const float* w1 = (const float*)d_in[1];
    const float* b1 = (const float*)d_in[2];
    const float* w2 = (const float*)d_in[3];
    const float* b2 = (const float*)d_in[4];
    const float* w3 = (const float*)d_in[5];
    const float* b3 = (const float*)d_in[6];
    const int*   ei = (const int*)d_in[7];

    const int N = in_sizes[0] / 256;   // 100000
    const int E = in_sizes[7] / 2;     // 1600000
    const int K1 = 256;

    float* out = (float*)d_out;

    // workspace carve-up (layout stable; _l weight slots unused)
    size_t nh = (size_t)N * 128;
    short* hs1    = (short*)d_ws;          // N*128 bf16 (raw h)
    short* hidH   = hs1 + nh;
    short* hidL   = hidH + nh;
    short* hs2    = hidL + nh;
    int*   cnt    = (int*)(hs2 + nh);
    float* dinv   = (float*)(cnt + N);
    int*   rowptr = (int*)(dinv + N);
    int*   cursor = rowptr + N;            // gcur[256]
    int*   bsum   = cursor + N;
    float* bcat   = (float*)(bsum + 512);
    short* w1t_h  = (short*)(bcat + 128);
    short* w1t_l  = w1t_h + 128 * 256;     // unused (R17)
    short* wct_h  = w1t_l + 128 * 256;
    short* wct_l  = wct_h + 128 * 128;     // unused (R17)
    int*   csr    = (int*)(wct_l + 128 * 128);

    const int* srcp = ei;
    const int* dstp = ei + E;

    const int ngrp = (N + GSIZE - 1) >> GSHIFT;   // 196
    int* gcur   = cursor;        // [256]
    int* staged = (int*)hs2;     // alias: 9.6MB; dead before gemm_bfin writes hs2

    // 0) zero group cursors (needed before kernel A's partition blocks)
    hipMemsetAsync(gcur, 0, 256 * sizeof(int), stream);

    // 1) A: prep (192 blocks) || partition
    int nPart = (E + PART_M - 1) / PART_M;
    prep_part<<<NPREP + nPart, TPB, 0, stream>>>(w1, w2, b2, w3, b3, w1t_h, wct_h,
                                                 bcat, srcp, dstp, gcur, staged, E);

    // 2) B: build_csr (196 blocks) || gemm1 BM=64 2-term (1563 blocks)
    int gtiles = (N + 63) / 64;
    csr_gemm1<<<ngrp + gtiles, TPB, 0, stream>>>(staged, gcur, cnt, dinv, rowptr, csr,
                                                 x, w1t_h, hs1, N, K1, ngrp);

    // 3) hidden = relu(dinv*(dinv*h_self + sum dinv_s*h_s) + b1) -> hi/lo bf16
    size_t gthreads = (size_t)N * 16;
    gather_hidden<<<(unsigned)((gthreads + TPB - 1) / TPB), TPB, 0, stream>>>(
        csr, rowptr, cnt, dinv, hs1, b1, hidH, hidL, N);

    // 4) hs2 = (hidden @ wcat_hi) * dinv -> bf16   (overwrites staged — dead by now)
    gemm_mfma_bfin<<<(N + 63) / 64, TPB, 0, stream>>>(hidH, hidL, wct_h, dinv, hs2, N, 128);

    // 5) out = dinv*(self+nbrs) + bcat -> mu | logvar (f32)
    gather_out<<<(unsigned)((gthreads + TPB - 1) / TPB), TPB, 0, stream>>>(
        csr, rowptr, cnt, dinv, hs2, bcat, out, N);
}